// Round 7
// baseline (196.992 us; speedup 1.0000x reference)
//
#include <hip/hip_runtime.h>
#include <cstdint>
#include <cstddef>

// ---------------------------------------------------------------------------
// Problem constants
// ---------------------------------------------------------------------------
#define NB   128      // batch
#define NPT  8192     // points per batch
#define NC   32       // centroids
#define NK   32       // group size
#define MSP  131072   // spatial size B*NC*NK for conv stack
#define R2   0.0625f  // radius^2

typedef unsigned short u16;
typedef unsigned long long u64;
typedef __attribute__((ext_vector_type(8))) short short8v;   // 8 bf16 = 4 VGPR (MFMA A/B frag)
typedef __attribute__((ext_vector_type(4))) float f32x4;     // MFMA C/D frag

// ws layout (float offsets)
static constexpr size_t OFF_CENTS  = 0;                        // 128*64
static constexpr size_t OFF_GX     = 8192;                     // 131072
static constexpr size_t OFF_GY     = OFF_GX + 131072;          // 131072
static constexpr size_t OFF_H1Q    = OFF_GY + 131072;          // overlay pool
static constexpr size_t OFF_H2Q    = OFF_H1Q + 4194304;        // bf16 [S][128] = 8388608 floats
// overlays of h1q region:
static constexpr size_t OFF_MAXPRE = OFF_H1Q;                  // 256*4096 = 1048576
static constexpr size_t OFF_P3S    = OFF_H1Q + 1048576;        // 256*4096
static constexpr size_t OFF_P3Q    = OFF_H1Q + 2097152;        // 256*4096
// overlays of h2q (dead after conv3):
static constexpr size_t OFF_PART1  = OFF_H2Q;                  // 64*131072 = 8388608 (exactly h2q size)
static constexpr size_t OFF_PART2  = OFF_H2Q;                  // 16*32768 (part1 dead when used)
static constexpr size_t OFF_FC1    = OFF_H2Q + 8388608;        // 128*1024
static constexpr size_t OFF_FC2    = OFF_FC1 + 131072;         // 128*256
static constexpr size_t OFF_W2Q    = OFF_FC2 + 32768;          // 8192 bf16 = 4096 floats
static constexpr size_t OFF_W3Q    = OFF_W2Q + 4096;           // 32768 bf16 = 16384 floats (frag-ordered)
static constexpr size_t OFF_PMOM   = OFF_W3Q + 16384;          // 5*4096
static constexpr size_t OFF_P2S    = OFF_PMOM + 20480;         // 128*1024
static constexpr size_t OFF_P2Q    = OFF_P2S + 131072;
static constexpr size_t OFF_SC1    = OFF_P2Q + 131072;
static constexpr size_t OFF_SH1    = OFF_SC1 + 64;
static constexpr size_t OFF_SC2    = OFF_SH1 + 64;
static constexpr size_t OFF_SH2    = OFF_SC2 + 128;
static constexpr size_t OFF_SC3    = OFF_SH2 + 128;
static constexpr size_t OFF_SH3    = OFF_SC3 + 256;
static constexpr size_t OFF_SC4    = OFF_SH3 + 256;
static constexpr size_t OFF_SH4    = OFF_SC4 + 1024;
static constexpr size_t OFF_SC5    = OFF_SH4 + 1024;
static constexpr size_t OFF_SH5    = OFF_SC5 + 256;
static constexpr size_t OFF_SC3E   = OFF_SH5 + 256;            // 8192 (bn3 per-k expanded)
static constexpr size_t OFF_SH3E   = OFF_SC3E + 8192;          // 8192

__device__ __forceinline__ u16 f2bf(float f) {          // RNE fp32->bf16
  uint32_t u = __float_as_uint(f);
  u += 0x7FFFu + ((u >> 16) & 1u);
  return (u16)(u >> 16);
}
__device__ __forceinline__ float bf2f(u16 h) {
  return __uint_as_float(((uint32_t)h) << 16);
}
// async global->LDS, 16B per lane; LDS dest = wave-uniform base + lane*16
__device__ __forceinline__ void gload16(const void* g, void* l) {
  __builtin_amdgcn_global_load_lds(
      (const __attribute__((address_space(1))) void*)g,
      (__attribute__((address_space(3))) void*)l, 16, 0, 0);
}

// ---------------------------------------------------------------------------
// 1) FPS: 128 blocks x 512 threads, 16 pts/thread. (dist,idx) packed in u64.
//    wquant folded into blocks 0..11.
// ---------------------------------------------------------------------------
__global__ __launch_bounds__(512) void fps_kernel(const float* __restrict__ x,
                                                  float* __restrict__ cents,
                                                  const float* __restrict__ c2w,
                                                  const float* __restrict__ c3w,
                                                  u16* __restrict__ w2q,
                                                  u16* __restrict__ w3qf) {
  const int b = blockIdx.x, t = threadIdx.x;
  const int lane = t & 63, wid = t >> 6;

  // ---- folded weight quant (6144 threads in blocks 0..11)
  if (b < 12) {
    const int id = b * 512 + t;
    if (id < 2048) {                                // w2q: 2048 x 4 elems
      const int e = id * 4;
      const float4 v = *(const float4*)(c2w + e);
      uint2 q;
      q.x = (uint32_t)f2bf(v.x) | ((uint32_t)f2bf(v.y) << 16);
      q.y = (uint32_t)f2bf(v.z) | ((uint32_t)f2bf(v.w) << 16);
      *(uint2*)(w2q + e) = q;
    } else {                                        // w3qf: 4096 x 8 elems
      const int id2 = id - 2048;                    // oc*16 + k8slot
      const int oc = id2 >> 4, k8 = (id2 & 15) * 8;
      const float4 v0 = *(const float4*)(c3w + oc * 128 + k8);
      const float4 v1 = *(const float4*)(c3w + oc * 128 + k8 + 4);
      uint4 q;
      q.x = (uint32_t)f2bf(v0.x) | ((uint32_t)f2bf(v0.y) << 16);
      q.y = (uint32_t)f2bf(v0.z) | ((uint32_t)f2bf(v0.w) << 16);
      q.z = (uint32_t)f2bf(v1.x) | ((uint32_t)f2bf(v1.y) << 16);
      q.w = (uint32_t)f2bf(v1.z) | ((uint32_t)f2bf(v1.w) << 16);
      const int off = ((((oc >> 4) * 4 + (k8 >> 5)) * 4 + ((k8 & 31) >> 3)) * 16 + (oc & 15)) * 8;
      *(uint4*)(w3qf + off) = q;
    }
  }

  const float* xb = x + (size_t)b * 2 * NPT;
  float px[16], py[16], dst[16];
  __shared__ float lpx[NPT], lpy[NPT];          // 64 KB point cache
  __shared__ u64 slot[2][8];
  __shared__ float cxs[NC], cys[NC];
#pragma unroll
  for (int k = 0; k < 16; k++) {
    const int id = t + k * 512;
    px[k] = xb[id];
    py[k] = xb[NPT + id];
    lpx[id] = px[k];
    lpy[id] = py[k];
  }
  const float c0x = xb[0], c0y = xb[NPT];       // broadcast loads
  if (t == 0) { cxs[0] = c0x; cys[0] = c0y; }
  u64 best = 0;
#pragma unroll
  for (int k = 0; k < 16; k++) {
    const float dx = __fsub_rn(c0x, px[k]);
    const float dy = __fsub_rn(c0y, py[k]);
    dst[k] = __fadd_rn(__fmul_rn(dx, dx), __fmul_rn(dy, dy));
    const u64 pk = ((u64)__float_as_uint(dst[k]) << 32) | (uint32_t)~(uint32_t)(t + k * 512);
    if (pk > best) best = pk;
  }
  __syncthreads();                              // lpx/lpy visible
  for (int j = 1; j < NC; j++) {
#pragma unroll
    for (int off = 1; off < 64; off <<= 1) {
      const u64 o = __shfl_xor(best, off);
      if (o > best) best = o;
    }
    const int pb = j & 1;
    if (lane == 0) slot[pb][wid] = best;
    __syncthreads();
    u64 w = slot[pb][0];
#pragma unroll
    for (int s = 1; s < 8; s++) {
      const u64 o = slot[pb][s];
      if (o > w) w = o;
    }
    const int wi = (int)~(uint32_t)w;
    const float wx = lpx[wi], wy = lpy[wi];
    if (t == 0) { cxs[j] = wx; cys[j] = wy; }
    best = 0;
#pragma unroll
    for (int k = 0; k < 16; k++) {
      const float dx = __fsub_rn(wx, px[k]);
      const float dy = __fsub_rn(wy, py[k]);
      const float nd = __fadd_rn(__fmul_rn(dx, dx), __fmul_rn(dy, dy));
      dst[k] = fminf(dst[k], nd);
      const u64 pk = ((u64)__float_as_uint(dst[k]) << 32) | (uint32_t)~(uint32_t)(t + k * 512);
      if (pk > best) best = pk;
    }
  }
  __syncthreads();
  if (t < NC) {
    cents[(size_t)b * 64 + t]      = cxs[t];
    cents[(size_t)b * 64 + 32 + t] = cys[t];
  }
}

// ---------------------------------------------------------------------------
// 2) Grouping v3: 8 CENTROIDS per block. Grid 512 = 4 cgroups x 128 batches.
// ---------------------------------------------------------------------------
__global__ __launch_bounds__(512) void group_kernel(const float* __restrict__ x,
                                                    const float* __restrict__ cents,
                                                    float* __restrict__ gx,
                                                    float* __restrict__ gy,
                                                    float* __restrict__ pmom) {
  const int b  = blockIdx.x & 127;
  const int cg = blockIdx.x >> 7;               // 0..3 -> centroids cg*8..cg*8+7
  const int t = threadIdx.x;
  const int lane = t & 63, wid = t >> 6;
  const float* px = x + (size_t)b * 2 * NPT;
  const float* py = px + NPT;
  const int p0 = t * 16;

  float lx[16], ly[16], sp[16];
#pragma unroll
  for (int k = 0; k < 16; k += 4) {
    const float4 vx = *(const float4*)(px + p0 + k);
    const float4 vy = *(const float4*)(py + p0 + k);
    lx[k] = vx.x; lx[k + 1] = vx.y; lx[k + 2] = vx.z; lx[k + 3] = vx.w;
    ly[k] = vy.x; ly[k + 1] = vy.y; ly[k + 2] = vy.z; ly[k + 3] = vy.w;
  }
#pragma unroll
  for (int k = 0; k < 16; k++)
    sp[k] = __fadd_rn(__fmul_rn(lx[k], lx[k]), __fmul_rn(ly[k], ly[k]));

  __shared__ int idxs[8][NK];
  __shared__ int wtot[8][8];
  uint32_t mask[8];
  int ebase[8];

#pragma unroll
  for (int c = 0; c < 8; c++) {
    const int cc = cg * 8 + c;
    const float cx = cents[(size_t)b * 64 + cc];
    const float cy = cents[(size_t)b * 64 + 32 + cc];
    const float sc = __fadd_rn(__fmul_rn(cx, cx), __fmul_rn(cy, cy));
    uint32_t m = 0;
#pragma unroll
    for (int k = 0; k < 16; k++) {
      const float dot = __fadd_rn(__fmul_rn(cx, lx[k]), __fmul_rn(cy, ly[k]));
      const float sq  = __fadd_rn(__fadd_rn(__fmul_rn(-2.0f, dot), sc), sp[k]);
      if (!(sq > R2)) m |= (1u << k);
    }
    mask[c] = m;
    const int cnt = (int)__popc(m);
    int pre = cnt;                              // inclusive scan within wave
#pragma unroll
    for (int off = 1; off < 64; off <<= 1) {
      const int o = __shfl_up(pre, off);
      if (lane >= off) pre += o;
    }
    ebase[c] = pre - cnt;                       // exclusive within wave
    if (lane == 63) wtot[c][wid] = pre;         // wave total
  }
  __syncthreads();
#pragma unroll
  for (int c = 0; c < 8; c++) {
    int off = 0;
#pragma unroll
    for (int w = 0; w < 8; w++) off += (w < wid) ? wtot[c][w] : 0;
    int pos = ebase[c] + off;                   // global ordered position
    uint32_t m = mask[c];
    while (m && pos < NK) {
      const int k = __ffs(m) - 1;
      idxs[c][pos] = p0 + k;
      m &= m - 1;
      pos++;
    }
  }
  __syncthreads();
  {                                             // pad short groups with idxs[0]
    int tot = 0;
#pragma unroll
    for (int w = 0; w < 8; w++) tot += wtot[wid][w];
    if (lane >= tot && lane < NK) idxs[wid][lane] = idxs[wid][0];
  }
  __syncthreads();
  {                                             // gather + fused moments (wave=cent)
    const int bc = b * 32 + cg * 8 + wid;
    float gxv = 0.f, gyv = 0.f;
    if (lane < NK) {
      const int id = idxs[wid][lane];
      gxv = px[id];
      gyv = py[id];
      const size_t s = (size_t)bc * NK + lane;
      gx[s] = gxv;
      gy[s] = gyv;
    }
    float sx = gxv, sy = gyv;
    float sxx = gxv * gxv, syy = gyv * gyv, sxy = gxv * gyv;
#pragma unroll
    for (int off = 1; off < 64; off <<= 1) {
      sx  += __shfl_xor(sx, off);
      sy  += __shfl_xor(sy, off);
      sxx += __shfl_xor(sxx, off);
      syy += __shfl_xor(syy, off);
      sxy += __shfl_xor(sxy, off);
    }
    if (lane == 0) {
      pmom[0 * 4096 + bc] = sx;
      pmom[1 * 4096 + bc] = sy;
      pmom[2 * 4096 + bc] = sxx;
      pmom[3 * 4096 + bc] = syy;
      pmom[4 * 4096 + bc] = sxy;
    }
  }
}

// bn1 scale/shift from moments: h1_c = w0*x + w1*y (bias BN-invariant, dropped)
__global__ __launch_bounds__(256) void bn1fin_kernel(const float* __restrict__ pmom,
                                                     const float* __restrict__ w,
                                                     const float* __restrict__ gamma,
                                                     const float* __restrict__ beta,
                                                     float* __restrict__ sc,
                                                     float* __restrict__ sh) {
  const int t = threadIdx.x, lane = t & 63, wid = t >> 6;
  __shared__ float rr[5][4];
  __shared__ float red[5];
#pragma unroll
  for (int m = 0; m < 5; m++) {
    float a = 0.f;
#pragma unroll
    for (int i = 0; i < 4; i++) {
      const float4 v = *(const float4*)(pmom + m * 4096 + (t + i * 256) * 4);
      a += v.x + v.y + v.z + v.w;
    }
#pragma unroll
    for (int off = 1; off < 64; off <<= 1) a += __shfl_xor(a, off);
    if (lane == 0) rr[m][wid] = a;
  }
  __syncthreads();
  if (t == 0) {
#pragma unroll
    for (int m = 0; m < 5; m++) red[m] = rr[m][0] + rr[m][1] + rr[m][2] + rr[m][3];
  }
  __syncthreads();
  if (t < 64) {
    const double invM = 1.0 / (double)MSP;
    const double mx = red[0] * invM, my = red[1] * invM;
    const double exx = red[2] * invM, eyy = red[3] * invM, exy = red[4] * invM;
    const double w0 = w[2 * t], w1 = w[2 * t + 1];
    const double mean = w0 * mx + w1 * my;
    double var = w0 * w0 * (exx - mx * mx) + 2.0 * w0 * w1 * (exy - mx * my)
               + w1 * w1 * (eyy - my * my);
    if (var < 0.0) var = 0.0;
    const double s = (double)gamma[t] / sqrt(var + 1e-5);
    sc[t] = (float)s;
    sh[t] = (float)((double)beta[t] - mean * s);
  }
}

// ---------------------------------------------------------------------------
// BN finalize: partials -> scale/shift (+ optional per-k expanded copy)
// ---------------------------------------------------------------------------
__global__ __launch_bounds__(256) void finalize_kernel(
    const float* __restrict__ psum, const float* __restrict__ psq,
    int P, float invM,
    const float* __restrict__ gamma, const float* __restrict__ beta,
    float* __restrict__ scale, float* __restrict__ shift,
    float* __restrict__ scexp, float* __restrict__ shexp, int expand) {
  const int c = blockIdx.x, t = threadIdx.x;
  float s = 0.f, q = 0.f;
  for (int p = t; p < P; p += 256) {
    s += psum[(size_t)c * P + p];
    q += psq[(size_t)c * P + p];
  }
#pragma unroll
  for (int off = 1; off < 64; off <<= 1) {
    s += __shfl_xor(s, off);
    q += __shfl_xor(q, off);
  }
  __shared__ float r1[4], r2[4], bc2[2];
  if ((t & 63) == 0) { r1[t >> 6] = s; r2[t >> 6] = q; }
  __syncthreads();
  if (t == 0) {
    s = r1[0] + r1[1] + r1[2] + r1[3];
    q = r2[0] + r2[1] + r2[2] + r2[3];
    const float m = s * invM;
    float v = fmaf(-m, m, q * invM);
    v = fmaxf(v, 0.f);
    const float sc = gamma[c] * (float)(1.0 / sqrt((double)v + 1e-5));
    const float sh = fmaf(-m, sc, beta[c]);
    scale[c] = sc;
    shift[c] = sh;
    bc2[0] = sc;
    bc2[1] = sh;
  }
  __syncthreads();
  if (t < expand) {
    scexp[c * expand + t] = bc2[0];
    shexp[c * expand + t] = bc2[1];
  }
}

// ---------------------------------------------------------------------------
// column BN (fc layers)
// ---------------------------------------------------------------------------
__global__ __launch_bounds__(256) void bncol_kernel(
    const float* __restrict__ in, int rows, int cols,
    const float* __restrict__ gamma, const float* __restrict__ beta,
    float* __restrict__ scale, float* __restrict__ shift) {
  const int jl = threadIdx.x & 63;
  const int rg = threadIdx.x >> 6;            // 0..3
  const int j = blockIdx.x * 64 + jl;
  float s = 0.f, q = 0.f;
  for (int r = rg; r < rows; r += 4) {
    const float v = in[(size_t)r * cols + j];
    s += v;
    q = fmaf(v, v, q);
  }
  __shared__ float rs[4][64], rq[4][64];
  rs[rg][jl] = s;
  rq[rg][jl] = q;
  __syncthreads();
  if (rg == 0) {
    s = rs[0][jl] + rs[1][jl] + rs[2][jl] + rs[3][jl];
    q = rq[0][jl] + rq[1][jl] + rq[2][jl] + rq[3][jl];
    const float m = s / (float)rows;
    float var = q / (float)rows - m * m;
    var = fmaxf(var, 0.f);
    const float sc = gamma[j] * (float)(1.0 / sqrt((double)var + 1e-5));
    scale[j] = sc;
    shift[j] = fmaf(-m, sc, beta[j]);
  }
}

// ---------------------------------------------------------------------------
// conv2 FUSED (conv1 inlined): D[oc][s], K=64, 512 thr = 8 waves (2 oc x 4 s).
// act tile [128 s][64 ch] computed from gx/gy on stage (bn1+relu+bf16).
// Emits h2q + bn2 partial stats (psum/psq).
// ---------------------------------------------------------------------------
__global__ __launch_bounds__(512) void conv2fused_kernel(
    const float* __restrict__ gx, const float* __restrict__ gy,
    const float* __restrict__ w1,     // conv1 weights [64][2] fp32
    const float* __restrict__ sc1, const float* __restrict__ sh1,
    const u16* __restrict__ wq,       // w2q [128][64] bf16
    u16* __restrict__ outq,           // h2q [S][128] bf16
    float* __restrict__ psum, float* __restrict__ psq) {   // [128][1024]
  constexpr int K = 64, OCB = 128, BS = 128, OCT = 128;
  constexpr int RB = K * 2;                       // 128 row bytes
  constexpr int STAGE = (OCB + BS) * RB;          // 32768
  constexpr int EPI = BS * OCB * 2 + 4 * OCB * 2 * 4;   // 36864
  constexpr int SMEM = STAGE > EPI ? STAGE : EPI;
  __shared__ __align__(16) char smem[SMEM + 1024];
  char* Wl = smem;                                // [128][64] bf16, byte^=(oc&7)<<4
  char* Bl = smem + OCB * RB;                     // [128][64] bf16, byte^=(s&7)<<4
  float* par = (float*)(smem + SMEM);             // w0[64] w1[64] sc[64] sh[64]
  const int t = threadIdx.x;
  const int lane = t & 63, wid = t >> 6;
  const int sblk = blockIdx.x;
  const int s_base = sblk * BS;

  if (t < 64) {
    par[t]       = w1[t * 2];
    par[64 + t]  = w1[t * 2 + 1];
    par[128 + t] = sc1[t];
    par[192 + t] = sh1[t];
  }
  __syncthreads();                                // par visible

  // ---- async W -> LDS (swizzled source, linear dest); overlaps act compute
  {
    constexpr int CH = OCB * RB / 16, PW = CH / 8, NI = PW / 64;  // 1024,128,2
#pragma unroll
    for (int j = 0; j < NI; j++) {
      const int c = wid * PW + j * 64 + lane;
      const int b = c * 16;
      const int oc = b / RB;
      const int off = b & (RB - 1);
      gload16((const char*)wq + (size_t)oc * RB + (off ^ ((oc & 7) << 4)),
              Wl + (wid * PW + j * 64) * 16);
    }
  }
  // ---- act tile from gx/gy (fused conv1: bn1+relu, bit-identical chain)
  {
    const int sl = t >> 2;                        // 0..127
    const int cq = t & 3;                         // 16-channel group
    const float xx = gx[s_base + sl], yy = gy[s_base + sl];
    uint32_t pk[8];
#pragma unroll
    for (int h = 0; h < 8; h++) {
      const int c = cq * 16 + 2 * h;
      float v0 = fmaf(par[c],     xx, par[64 + c]     * yy);
      float v1 = fmaf(par[c + 1], xx, par[64 + c + 1] * yy);
      v0 = fmaxf(fmaf(v0, par[128 + c],     par[192 + c]),     0.f);
      v1 = fmaxf(fmaf(v1, par[128 + c + 1], par[192 + c + 1]), 0.f);
      pk[h] = (uint32_t)f2bf(v0) | ((uint32_t)f2bf(v1) << 16);
    }
    *(uint4*)(Bl + sl * RB + ((cq * 32)      ^ ((sl & 7) << 4))) = *(uint4*)&pk[0];
    *(uint4*)(Bl + sl * RB + ((cq * 32 + 16) ^ ((sl & 7) << 4))) = *(uint4*)&pk[4];
  }
  __syncthreads();                                // W gloads drained + Bl visible

  // ---- MFMA main: wave (wr,wc) computes oc[wr*64..+64) x s[wc*32..+32)
  const int wr = wid >> 2, wc = wid & 3;
  const int l15 = lane & 15, l4 = lane >> 4;
  f32x4 acc[4][2];
#pragma unroll
  for (int fo = 0; fo < 4; fo++)
#pragma unroll
    for (int fs = 0; fs < 2; fs++)
#pragma unroll
      for (int q = 0; q < 4; q++) acc[fo][fs][q] = 0.f;

#pragma unroll
  for (int ks = 0; ks < K / 32; ks++) {
    short8v a[4], bv[2];
#pragma unroll
    for (int f = 0; f < 4; f++) {
      const int oc = wr * 64 + f * 16 + l15;
      a[f] = *(const short8v*)(Wl + oc * RB + ((ks * 64 + l4 * 16) ^ ((oc & 7) << 4)));
    }
#pragma unroll
    for (int f = 0; f < 2; f++) {
      const int sl = wc * 32 + f * 16 + l15;
      bv[f] = *(const short8v*)(Bl + sl * RB + ((ks * 64 + l4 * 16) ^ ((sl & 7) << 4)));
    }
#pragma unroll
    for (int fo = 0; fo < 4; fo++)
#pragma unroll
      for (int fs = 0; fs < 2; fs++)
        acc[fo][fs] = __builtin_amdgcn_mfma_f32_16x16x32_bf16(a[fo], bv[fs], acc[fo][fs], 0, 0, 0);
  }
  __syncthreads();   // staging LDS dead; reuse for epilogue

  char* Dl = smem;                                // [BS][OCB] bf16 swizzled
  float* sred1 = (float*)(smem + BS * OCB * 2);
  float* sred2 = sred1 + 4 * OCB;

#pragma unroll
  for (int fo = 0; fo < 4; fo++)
#pragma unroll
    for (int r = 0; r < 4; r++) {
      float s1 = acc[fo][0][r] + acc[fo][1][r];
      float s2 = fmaf(acc[fo][0][r], acc[fo][0][r], acc[fo][1][r] * acc[fo][1][r]);
#pragma unroll
      for (int off = 1; off < 16; off <<= 1) {
        s1 += __shfl_xor(s1, off);
        s2 += __shfl_xor(s2, off);
      }
      if (l15 == 0) {
        const int ocl = wr * 64 + fo * 16 + l4 * 4 + r;
        sred1[wc * OCB + ocl] = s1;
        sred2[wc * OCB + ocl] = s2;
      }
    }

#pragma unroll
  for (int fo = 0; fo < 4; fo++)
#pragma unroll
    for (int fs = 0; fs < 2; fs++) {
      const int sl = wc * 32 + fs * 16 + l15;
      const int ocl = wr * 64 + fo * 16 + l4 * 4;
      uint2 q;
      q.x = (uint32_t)f2bf(acc[fo][fs][0]) | ((uint32_t)f2bf(acc[fo][fs][1]) << 16);
      q.y = (uint32_t)f2bf(acc[fo][fs][2]) | ((uint32_t)f2bf(acc[fo][fs][3]) << 16);
      *(uint2*)(Dl + sl * 256 + ((ocl * 2) ^ ((sl & 7) << 4))) = q;
    }
  __syncthreads();

  if (t < OCB) {
    psum[(size_t)t * 1024 + sblk] =
        sred1[t] + sred1[OCB + t] + sred1[2 * OCB + t] + sred1[3 * OCB + t];
    psq[(size_t)t * 1024 + sblk] =
        sred2[t] + sred2[OCB + t] + sred2[2 * OCB + t] + sred2[3 * OCB + t];
  }
#pragma unroll
  for (int i = 0; i < 4; i++) {
    const int c = t + i * 512;                   // 2048 16B-chunks
    const int sl = c >> 4, slot = c & 15;
    const uint4 v = *(const uint4*)(Dl + sl * 256 + ((slot * 16) ^ ((sl & 7) << 4)));
    *(uint4*)(outq + (size_t)(s_base + sl) * OCT + slot * 8) = v;
  }
}

// ---------------------------------------------------------------------------
// conv3 v4: one-shot, 512 thr = 8 waves (2s x 4oc) covering ALL 256 oc.
// W in REGISTERS from frag-ordered w3qf; act tile 64s x 128k in LDS
// (bn2+relu applied on stage). SWAPPED MFMA: D[s][oc]; stats+max at gid=32s.
// ---------------------------------------------------------------------------
__global__ __launch_bounds__(512) void conv3_kernel(
    const u16* __restrict__ act,      // h2q [S][128] bf16 (raw, pre-bn2)
    const u16* __restrict__ wqf,      // frag-ordered [256][128]
    const float* __restrict__ ascale, const float* __restrict__ ashift,  // bn2, len 128
    float* __restrict__ psum, float* __restrict__ psq,   // [256][4096]
    float* __restrict__ maxpre) {     // [256][4096]
  constexpr int K = 128, RB = 256;
  __shared__ __align__(16) char Bl[64 * RB];      // 16KB act tile, swizzled
  const int t = threadIdx.x;
  const int lane = t & 63, wid = t >> 6;
  const int ws = wid & 1, wo = wid >> 1;          // s-half (0..1), oc-quarter (0..3)
  const int sblk = blockIdx.x;                    // 0..2047: 64-row s-tile
  const int l15 = lane & 15, l4 = lane >> 4;
  const int s_base = sblk * 64;

  // ---- W frags into registers: b[fo][ks], coalesced 1KB loads
  short8v b[4][4];
  {
    const int ocq0 = wo * 4;
#pragma unroll
    for (int fo = 0; fo < 4; fo++)
#pragma unroll
      for (int ks = 0; ks < 4; ks++)
        b[fo][ks] = *(const short8v*)(wqf + ((((ocq0 + fo) * 4 + ks) * 4 + l4) * 16 + l15) * 8);
  }

  // ---- stage act tile with bn2+relu (reg -> transform -> swizzled LDS)
  {
    const int kk0 = (t & 15) * 8;
    const float4 scA = *(const float4*)(ascale + kk0);
    const float4 scB = *(const float4*)(ascale + kk0 + 4);
    const float4 shA = *(const float4*)(ashift + kk0);
    const float4 shB = *(const float4*)(ashift + kk0 + 4);
    const float scr[8] = {scA.x, scA.y, scA.z, scA.w, scB.x, scB.y, scB.z, scB.w};
    const float shr[8] = {shA.x, shA.y, shA.z, shA.w, shB.x, shB.y, shB.z, shB.w};
#pragma unroll
    for (int i = 0; i < 2; i++) {
      const int sl = (t >> 4) + i * 32;
      const uint4 raw = *(const uint4*)(act + (size_t)(s_base + sl) * K + kk0);
      const u16* rp = (const u16*)&raw;
      uint32_t pk[4];
#pragma unroll
      for (int h = 0; h < 4; h++) {
        const float f0 = fmaxf(fmaf(bf2f(rp[2 * h]),     scr[2 * h],     shr[2 * h]),     0.f);
        const float f1 = fmaxf(fmaf(bf2f(rp[2 * h + 1]), scr[2 * h + 1], shr[2 * h + 1]), 0.f);
        pk[h] = (uint32_t)f2bf(f0) | ((uint32_t)f2bf(f1) << 16);
      }
      *(uint4*)(Bl + sl * RB + ((kk0 * 2) ^ ((sl & 7) << 4))) = *(uint4*)pk;
    }
  }
  __syncthreads();

  // ---- swapped MFMA: A = act (s side), B = W (oc side) -> D[s][oc]
  f32x4 acc[2][4];
#pragma unroll
  for (int fs = 0; fs < 2; fs++)
#pragma unroll
    for (int fo = 0; fo < 4; fo++)
#pragma unroll
      for (int q = 0; q < 4; q++) acc[fs][fo][q] = 0.f;

#pragma unroll
  for (int ks = 0; ks < 4; ks++) {
    short8v a[2];
#pragma unroll
    for (int fs = 0; fs < 2; fs++) {
      const int srow = ws * 32 + fs * 16 + l15;
      a[fs] = *(const short8v*)(Bl + srow * RB + ((ks * 64 + l4 * 16) ^ ((srow & 7) << 4)));
    }
#pragma unroll
    for (int fs = 0; fs < 2; fs++)
#pragma unroll
      for (int fo = 0; fo < 4; fo++)
        acc[fs][fo] = __builtin_amdgcn_mfma_f32_16x16x32_bf16(a[fs], b[fo][ks], acc[fs][fo], 0, 0, 0);
  }

  // ---- epilogue: per oc column, sum/sq/max over this wave's 32 s
  const int gid = sblk * 2 + ws;                  // 32-s pool group id
#pragma unroll
  for (int fo = 0; fo < 4; fo++) {
    float s1 = acc[0][fo][0], s2 = acc[0][fo][0] * acc[0][fo][0];
    float mx = acc[0][fo][0];
#pragma unroll
    for (int fs = 0; fs < 2; fs++)
#pragma unroll
      for (int r = 0; r < 4; r++) {
        if (fs == 0 && r == 0) continue;
        const float v = acc[fs][fo][r];
        s1 += v;
        s2 = fmaf(v, v, s2);
        mx = fmaxf(mx, v);
      }
    s1 += __shfl_xor(s1, 16); s1 += __shfl_xor(s1, 32);
    s2 += __shfl_xor(s2, 16); s2 += __shfl_xor(s2, 32);
    mx = fmaxf(mx, __shfl_xor(mx, 16));
    mx = fmaxf(mx, __shfl_xor(mx, 32));
    if (l4 == 0) {
      const int oc = wo * 64 + fo * 16 + l15;
      psum[(size_t)oc * 4096 + gid] = s1;
      psq [(size_t)oc * 4096 + gid] = s2;
      maxpre[(size_t)oc * 4096 + gid] = mx;
    }
  }
}

// ---------------------------------------------------------------------------
// fc1/fc2 via MFMA with in-register bf16 hi/lo SPLIT (fp32-class accuracy).
// T14 async-stage split: next k-chunk's W/A float4 loads issued into
// registers right after the barrier, hiding HBM latency under the MFMAs.
// ---------------------------------------------------------------------------
template <int KL, bool TRANS, bool GATHER>
__global__ __launch_bounds__(512) void fcmfma_kernel(
    const float* __restrict__ A,      // [128][Ktot] fp32, or maxpre if GATHER
    const float* __restrict__ W,      // [Ntot][Ktot] fp32
    const float* __restrict__ ascale, const float* __restrict__ ashift,
    float* __restrict__ part,         // [Ktot/KL][128][Ntot]
    int Ntot, int Ktot) {
  __shared__ __align__(16) char smem[65536];
  char* Wh = smem;                    // each [128][64] bf16, rowbytes 128,
  char* Wl = smem + 16384;            // byte ^= (row&7)<<4
  char* Ah = smem + 32768;
  char* Al = smem + 49152;
  const int t = threadIdx.x;
  const int lane = t & 63, wid = t >> 6;
  const int sblk = blockIdx.x;        // k-split index
  const int n_base = blockIdx.y * 128;
  const int k_begin = sblk * KL;
  const int kq = t & 15;              // float4-slot in row (constant per thread)
  const int r0 = t >> 4;              // rows r0, r0+32, r0+64, r0+96
  const int kk = kq * 4;
  const int wn = wid & 1, wm = wid >> 1;
  const int l15 = lane & 15, l4 = lane >> 4;

  f32x4 acc[4][2];
#pragma unroll
  for (int fo = 0; fo < 4; fo++)
#pragma unroll
    for (int fs = 0; fs < 2; fs++)
#pragma unroll
      for (int q = 0; q < 4; q++) acc[fo][fs][q] = 0.f;

  float4 wv[4], av[4], tsc, tsh;
  // ---- prologue: load chunk 0 into registers
  {
    const int kabs = k_begin + kk;
    if constexpr (TRANS) {
      tsc = *(const float4*)(ascale + kabs);
      tsh = *(const float4*)(ashift + kabs);
    }
#pragma unroll
    for (int i = 0; i < 4; i++) {
      const int row = r0 + i * 32;
      wv[i] = *(const float4*)(W + (size_t)(n_base + row) * Ktot + kabs);
      if constexpr (GATHER)
        av[i] = *(const float4*)(A + (size_t)(kabs >> 5) * 4096 + row * 32 + (kabs & 31));
      else
        av[i] = *(const float4*)(A + (size_t)row * Ktot + kabs);
    }
  }

  for (int c0 = 0; c0 < KL; c0 += 64) {
    // ---- convert current regs -> LDS (same chain as before)
#pragma unroll
    for (int i = 0; i < 4; i++) {
      const int row = r0 + i * 32;
      const int byte = row * 128 + ((kk * 2) ^ ((row & 7) << 4));
      {
        const float4 v = wv[i];
        const u16 h0 = f2bf(v.x), h1 = f2bf(v.y), h2 = f2bf(v.z), h3 = f2bf(v.w);
        uint2 hv, lv;
        hv.x = (uint32_t)h0 | ((uint32_t)h1 << 16);
        hv.y = (uint32_t)h2 | ((uint32_t)h3 << 16);
        lv.x = (uint32_t)f2bf(v.x - bf2f(h0)) | ((uint32_t)f2bf(v.y - bf2f(h1)) << 16);
        lv.y = (uint32_t)f2bf(v.z - bf2f(h2)) | ((uint32_t)f2bf(v.w - bf2f(h3)) << 16);
        *(uint2*)(Wh + byte) = hv;
        *(uint2*)(Wl + byte) = lv;
      }
      {
        float4 v = av[i];
        if constexpr (TRANS) {
          v.x = fmaxf(fmaf(v.x, tsc.x, tsh.x), 0.f);
          v.y = fmaxf(fmaf(v.y, tsc.y, tsh.y), 0.f);
          v.z = fmaxf(fmaf(v.z, tsc.z, tsh.z), 0.f);
          v.w = fmaxf(fmaf(v.w, tsc.w, tsh.w), 0.f);
        }
        const u16 h0 = f2bf(v.x), h1 = f2bf(v.y), h2 = f2bf(v.z), h3 = f2bf(v.w);
        uint2 hv, lv;
        hv.x = (uint32_t)h0 | ((uint32_t)h1 << 16);
        hv.y = (uint32_t)h2 | ((uint32_t)h3 << 16);
        lv.x = (uint32_t)f2bf(v.x - bf2f(h0)) | ((uint32_t)f2bf(v.y - bf2f(h1)) << 16);
        lv.y = (uint32_t)f2bf(v.z - bf2f(h2)) | ((uint32_t)f2bf(v.w - bf2f(h3)) << 16);
        *(uint2*)(Ah + byte) = hv;
        *(uint2*)(Al + byte) = lv;
      }
    }
    __syncthreads();
    // ---- prefetch next chunk (loads stay in flight across the MFMA phase)
    if (c0 + 64 < KL) {
      const int kabs = k_begin + c0 + 64 + kk;
      if constexpr (TRANS) {
        tsc = *(const float4*)(ascale + kabs);
        tsh = *(const float4*)(ashift + kabs);
      }
#pragma unroll
      for (int i = 0; i < 4; i++) {
        const int row = r0 + i * 32;
        wv[i] = *(const float4*)(W + (size_t)(n_base + row) * Ktot + kabs);
        if constexpr (GATHER)
          av[i] = *(const float4*)(A + (size_t)(kabs >> 5) * 4096 + row * 32 + (kabs & 31));
        else
          av[i] = *(const float4*)(A + (size_t)row * Ktot + kabs);
      }
    }
    // ---- MFMA phase
#pragma unroll
    for (int ks = 0; ks < 2; ks++) {
      short8v ah[4], al_[4], bh[2], bl[2];
#pragma unroll
      for (int f = 0; f < 4; f++) {
        const int r = wn * 64 + f * 16 + l15;
        const int byte = r * 128 + ((ks * 64 + l4 * 16) ^ ((r & 7) << 4));
        ah[f]  = *(const short8v*)(Wh + byte);
        al_[f] = *(const short8v*)(Wl + byte);
      }
#pragma unroll
      for (int f = 0; f < 2; f++) {
        const int r = wm * 32 + f * 16 + l15;
        const int byte = r * 128 + ((ks * 64 + l4 * 16) ^ ((r & 7) << 4));
        bh[f] = *(const short8v*)(Ah + byte);
        bl[f] = *(const short8v*)(Al + byte);
      }
#pragma unroll
      for (int fo = 0; fo < 4; fo++)
#pragma unroll
        for (int fs = 0; fs < 2; fs++) {
          acc[fo][fs] = __builtin_amdgcn_mfma_f32_16x16x32_bf16(ah[fo],  bh[fs], acc[fo][fs], 0, 0, 0);
          acc[fo][fs] = __builtin_amdgcn_mfma_f32_16x16x32_bf16(ah[fo],  bl[fs], acc[fo][fs], 0, 0, 0);
          acc[fo][fs] = __builtin_amdgcn_mfma_f32_16x16x32_bf16(al_[fo], bh[fs], acc[fo][fs], 0, 0, 0);
        }
    }
    __syncthreads();
  }
  // epilogue: D row = n (W side), col = m (batch side)
#pragma unroll
  for (int fo = 0; fo < 4; fo++) {
    const int n0 = n_base + wn * 64 + fo * 16 + l4 * 4;
#pragma unroll
    for (int fs = 0; fs < 2; fs++) {
      const int m = wm * 32 + fs * 16 + l15;
      *(float4*)(part + ((size_t)sblk * 128 + m) * Ntot + n0) =
          make_float4(acc[fo][fs][0], acc[fo][fs][1], acc[fo][fs][2], acc[fo][fs][3]);
    }
  }
}

// out[id] = sum_p part[p][id]  (id over 128*Ntot)
__global__ __launch_bounds__(256) void fcreduce_kernel(const float* __restrict__ part,
                                                       float* __restrict__ out,
                                                       int total, int S) {
  const int id = blockIdx.x * 256 + threadIdx.x;
  if (id >= total) return;
  float s = 0.f;
  for (int p = 0; p < S; p++) s += part[(size_t)p * total + id];
  out[id] = s;
}

// ---------------------------------------------------------------------------
// tail v3 (256 thr): bnrelu5 -> fc3 (8x8-lane split dot) -> mu/logvar -> z
// -> decoder -> outputs. Wider block for the d2/d3 dot phases.
// ---------------------------------------------------------------------------
__global__ __launch_bounds__(256) void tail_kernel(
    const float* __restrict__ fc2raw, const float* __restrict__ scale5, const float* __restrict__ shift5,
    const float* __restrict__ w3, const float* __restrict__ b3,
    const float* __restrict__ e1w, const float* __restrict__ e1b,
    const float* __restrict__ e2w, const float* __restrict__ e2b,
    const float* __restrict__ eps,
    const float* __restrict__ d1w, const float* __restrict__ d1b,
    const float* __restrict__ d2w, const float* __restrict__ d2b,
    const float* __restrict__ d3w, const float* __restrict__ d3b,
    float* __restrict__ out) {
  const int b = blockIdx.x, t = threadIdx.x;
  __shared__ float h5[256], feat[8], z[8], d1[32], d2[128];
  {
    const float v = fc2raw[(size_t)b * 256 + t];
    h5[t] = fmaxf(fmaf(v, scale5[t], shift5[t]), 0.f);
  }
  __syncthreads();
  if (t < 64) {                       // fc3: 8 outputs x 8 lanes x 32 FMA
    const int o = t >> 3, p = t & 7;
    const float* wr = w3 + o * 256 + p * 32;
    const float* hr = h5 + p * 32;
    float s = 0.f;
    for (int i = 0; i < 32; i++) s = fmaf(hr[i], wr[i], s);
    s += __shfl_xor(s, 1);
    s += __shfl_xor(s, 2);
    s += __shfl_xor(s, 4);
    if (p == 0) feat[o] = fmaxf(s + b3[o], 0.f);
  }
  __syncthreads();
  if (t < 8) {
    float mu = e1b[t], lv = e2b[t];
    for (int j = 0; j < 8; j++) {
      mu = fmaf(feat[j], e1w[t * 8 + j], mu);
      lv = fmaf(feat[j], e2w[t * 8 + j], lv);
    }
    out[65536 + b * 8 + t] = mu;
    out[66560 + b * 8 + t] = lv;
    z[t] = fmaf(eps[b * 8 + t], expf(0.5f * lv), mu);
  }
  __syncthreads();
  if (t < 32) {
    float s = d1b[t];
    for (int j = 0; j < 8; j++) s = fmaf(z[j], d1w[t * 8 + j], s);
    d1[t] = fmaxf(s, 0.f);
  }
  __syncthreads();
  if (t < 128) {
    float s = d2b[t];
    for (int j = 0; j < 32; j++) s = fmaf(d1[j], d2w[t * 32 + j], s);
    d2[t] = fmaxf(s, 0.f);
  }
  __syncthreads();
  for (int o = t; o < 512; o += 256) {
    float s = d3b[o];
    for (int j = 0; j < 128; j++) s = fmaf(d2[j], d3w[o * 128 + j], s);
    out[(size_t)b * 512 + o] = s;
  }
}

// ---------------------------------------------------------------------------
extern "C" void kernel_launch(void* const* d_in, const int* in_sizes, int n_in,
                              void* d_out, int out_size, void* d_ws, size_t ws_size,
                              hipStream_t stream) {
  const float* x    = (const float*)d_in[0];
  const float* eps  = (const float*)d_in[1];
  const float* c1w  = (const float*)d_in[2];
  const float* bn1g = (const float*)d_in[4];
  const float* bn1b = (const float*)d_in[5];
  const float* c2w  = (const float*)d_in[6];
  const float* bn2g = (const float*)d_in[8];
  const float* bn2b = (const float*)d_in[9];
  const float* c3w  = (const float*)d_in[10];
  const float* bn3g = (const float*)d_in[12];
  const float* bn3b = (const float*)d_in[13];
  const float* f1w  = (const float*)d_in[14];
  const float* bn4g = (const float*)d_in[16];
  const float* bn4b = (const float*)d_in[17];
  const float* f2w  = (const float*)d_in[18];
  const float* bn5g = (const float*)d_in[20];
  const float* bn5b = (const float*)d_in[21];
  const float* f3w  = (const float*)d_in[22];
  const float* f3b  = (const float*)d_in[23];
  const float* e1w  = (const float*)d_in[24];
  const float* e1b  = (const float*)d_in[25];
  const float* e2w  = (const float*)d_in[26];
  const float* e2b  = (const float*)d_in[27];
  const float* d1w  = (const float*)d_in[28];
  const float* d1b  = (const float*)d_in[29];
  const float* d2w  = (const float*)d_in[30];
  const float* d2b  = (const float*)d_in[31];
  const float* d3w  = (const float*)d_in[32];
  const float* d3b  = (const float*)d_in[33];

  float* ws = (float*)d_ws;
  float* cents  = ws + OFF_CENTS;
  float* gx     = ws + OFF_GX;
  float* gy     = ws + OFF_GY;
  u16*   h2q    = (u16*)(ws + OFF_H2Q);
  u16*   w2q    = (u16*)(ws + OFF_W2Q);
  u16*   w3qf   = (u16*)(ws + OFF_W3Q);
  float* pmom   = ws + OFF_PMOM;
  float* maxpre = ws + OFF_MAXPRE;
  float* part1  = ws + OFF_PART1;
  float* part2  = ws + OFF_PART2;
  float* fc1o   = ws + OFF_FC1;
  float* fc2o   = ws + OFF_FC2;
  float* p2s = ws + OFF_P2S, *p2q = ws + OFF_P2Q;
  float* p3s = ws + OFF_P3S, *p3q = ws + OFF_P3Q;
  float* sc1 = ws + OFF_SC1, *sh1 = ws + OFF_SH1;
  float* sc2 = ws + OFF_SC2, *sh2 = ws + OFF_SH2;
  float* sc3 = ws + OFF_SC3, *sh3 = ws + OFF_SH3;
  float* sc4 = ws + OFF_SC4, *sh4 = ws + OFF_SH4;
  float* sc5 = ws + OFF_SC5, *sh5 = ws + OFF_SH5;
  float* sc3e = ws + OFF_SC3E, *sh3e = ws + OFF_SH3E;

  // fps v4: wquant folded into blocks 0..11
  fps_kernel<<<NB, 512, 0, stream>>>(x, cents, c2w, c3w, w2q, w3qf);
  // group v3: 4 cgroups x 128 batches, 8 centroids per block
  group_kernel<<<512, 512, 0, stream>>>(x, cents, gx, gy, pmom);

  bn1fin_kernel<<<1, 256, 0, stream>>>(pmom, c1w, bn1g, bn1b, sc1, sh1);

  // conv2 FUSED (conv1 inlined on stage): gx/gy -> h2q + bn2 stats
  conv2fused_kernel<<<1024, 512, 0, stream>>>(gx, gy, c1w, sc1, sh1, w2q,
                                              h2q, p2s, p2q);
  finalize_kernel<<<128, 256, 0, stream>>>(p2s, p2q, 1024, 1.f / MSP, bn2g, bn2b,
                                           sc2, sh2, nullptr, nullptr, 0);

  // conv3 v4: 512-thr blocks, one act stage per s-tile (all 256 oc in-block)
  conv3_kernel<<<2048, 512, 0, stream>>>(h2q, w3qf, sc2, sh2, p3s, p3q, maxpre);
  finalize_kernel<<<256, 256, 0, stream>>>(p3s, p3q, 4096, 1.f / MSP, bn3g, bn3b,
                                           sc3, sh3, sc3e, sh3e, 32);

  // fc1: N=1024, K=8192; KL=128 -> 64 k-splits, grid 512 blocks = 2/CU
  // (overlap convert-VALU of one block with MFMA of another; T14 prefetch)
  fcmfma_kernel<128, true, true><<<dim3(64, 8), 512, 0, stream>>>(
      maxpre, f1w, sc3e, sh3e, part1, 1024, 8192);
  fcreduce_kernel<<<512, 256, 0, stream>>>(part1, fc1o, 131072, 64);
  bncol_kernel<<<16, 256, 0, stream>>>(fc1o, 128, 1024, bn4g, bn4b, sc4, sh4);

  // fc2: N=256, K=1024, KL=64 -> 16 k-splits x 2 n-blocks = 32 blocks
  fcmfma_kernel<64, true, false><<<dim3(16, 2), 512, 0, stream>>>(
      fc1o, f2w, sc4, sh4, part2, 256, 1024);
  fcreduce_kernel<<<128, 256, 0, stream>>>(part2, fc2o, 32768, 16);
  bncol_kernel<<<4, 256, 0, stream>>>(fc2o, 128, 256, bn5g, bn5b, sc5, sh5);

  tail_kernel<<<NB, 256, 0, stream>>>(fc2o, sc5, sh5, f3w, f3b, e1w, e1b, e2w, e2b, eps,
                                      d1w, d1b, d2w, d2b, d3w, d3b, (float*)d_out);
}

// Round 8
// 188.773 us; speedup vs baseline: 1.0435x; 1.0435x over previous
//
#include <hip/hip_runtime.h>
#include <cstdint>
#include <cstddef>

// ---------------------------------------------------------------------------
// Problem constants
// ---------------------------------------------------------------------------
#define NB   128      // batch
#define NPT  8192     // points per batch
#define NC   32       // centroids
#define NK   32       // group size
#define MSP  131072   // spatial size B*NC*NK for conv stack
#define R2   0.0625f  // radius^2

typedef unsigned short u16;
typedef unsigned long long u64;
typedef __attribute__((ext_vector_type(8))) short short8v;   // 8 bf16 = 4 VGPR (MFMA A/B frag)
typedef __attribute__((ext_vector_type(4))) float f32x4;     // MFMA C/D frag

// ws layout (float offsets)
static constexpr size_t OFF_CENTS  = 0;                        // 128*64
static constexpr size_t OFF_GX     = 8192;                     // 131072
static constexpr size_t OFF_GY     = OFF_GX + 131072;          // 131072
static constexpr size_t OFF_H1Q    = OFF_GY + 131072;          // overlay pool
static constexpr size_t OFF_H2Q    = OFF_H1Q + 4194304;        // bf16 [S][128] = 8388608 floats
// overlays of h1q region:
static constexpr size_t OFF_MAXPRE = OFF_H1Q;                  // 256*4096 = 1048576
static constexpr size_t OFF_P3S    = OFF_H1Q + 1048576;        // 256*4096
static constexpr size_t OFF_P3Q    = OFF_H1Q + 2097152;        // 256*4096
// overlays of h2q (dead after conv3):
static constexpr size_t OFF_PART1  = OFF_H2Q;                  // 32*131072
static constexpr size_t OFF_PART2  = OFF_H2Q + 4194304;        // 8*32768
static constexpr size_t OFF_FC1    = OFF_H2Q + 8388608;        // 128*1024
static constexpr size_t OFF_FC2    = OFF_FC1 + 131072;         // 128*256
static constexpr size_t OFF_W2Q    = OFF_FC2 + 32768;          // 8192 bf16 = 4096 floats
static constexpr size_t OFF_W3Q    = OFF_W2Q + 4096;           // 32768 bf16 = 16384 floats (frag-ordered)
static constexpr size_t OFF_PMOM   = OFF_W3Q + 16384;          // 5*4096
static constexpr size_t OFF_P2S    = OFF_PMOM + 20480;         // 128*1024
static constexpr size_t OFF_P2Q    = OFF_P2S + 131072;
static constexpr size_t OFF_SC1    = OFF_P2Q + 131072;
static constexpr size_t OFF_SH1    = OFF_SC1 + 64;
static constexpr size_t OFF_SC2    = OFF_SH1 + 64;
static constexpr size_t OFF_SH2    = OFF_SC2 + 128;
static constexpr size_t OFF_SC3    = OFF_SH2 + 128;
static constexpr size_t OFF_SH3    = OFF_SC3 + 256;
static constexpr size_t OFF_SC4    = OFF_SH3 + 256;
static constexpr size_t OFF_SH4    = OFF_SC4 + 1024;
static constexpr size_t OFF_SC5    = OFF_SH4 + 1024;
static constexpr size_t OFF_SH5    = OFF_SC5 + 256;
static constexpr size_t OFF_SC3E   = OFF_SH5 + 256;            // 8192 (bn3 per-k expanded)
static constexpr size_t OFF_SH3E   = OFF_SC3E + 8192;          // 8192

__device__ __forceinline__ u16 f2bf(float f) {          // RNE fp32->bf16
  uint32_t u = __float_as_uint(f);
  u += 0x7FFFu + ((u >> 16) & 1u);
  return (u16)(u >> 16);
}
__device__ __forceinline__ float bf2f(u16 h) {
  return __uint_as_float(((uint32_t)h) << 16);
}
// async global->LDS, 16B per lane; LDS dest = wave-uniform base + lane*16
__device__ __forceinline__ void gload16(const void* g, void* l) {
  __builtin_amdgcn_global_load_lds(
      (const __attribute__((address_space(1))) void*)g,
      (__attribute__((address_space(3))) void*)l, 16, 0, 0);
}

// ---------------------------------------------------------------------------
// 1) FPS: 128 blocks x 512 threads, 16 pts/thread. wquant folded into
//    blocks 0..11. v5: per-element float argmax (2 VALU/elem) replaces the
//    u64 pack+cmp (~6 ops/elem) on the 31-iteration serial critical path;
//    one u64 pack per iteration. Selection bit-identical (dist>=0 so float
//    order == bit order; strict > keeps smallest index, matching ~idx).
// ---------------------------------------------------------------------------
__global__ __launch_bounds__(512) void fps_kernel(const float* __restrict__ x,
                                                  float* __restrict__ cents,
                                                  const float* __restrict__ c2w,
                                                  const float* __restrict__ c3w,
                                                  u16* __restrict__ w2q,
                                                  u16* __restrict__ w3qf) {
  const int b = blockIdx.x, t = threadIdx.x;
  const int lane = t & 63, wid = t >> 6;

  // ---- folded weight quant (6144 threads in blocks 0..11)
  if (b < 12) {
    const int id = b * 512 + t;
    if (id < 2048) {                                // w2q: 2048 x 4 elems
      const int e = id * 4;
      const float4 v = *(const float4*)(c2w + e);
      uint2 q;
      q.x = (uint32_t)f2bf(v.x) | ((uint32_t)f2bf(v.y) << 16);
      q.y = (uint32_t)f2bf(v.z) | ((uint32_t)f2bf(v.w) << 16);
      *(uint2*)(w2q + e) = q;
    } else {                                        // w3qf: 4096 x 8 elems
      const int id2 = id - 2048;                    // oc*16 + k8slot
      const int oc = id2 >> 4, k8 = (id2 & 15) * 8;
      const float4 v0 = *(const float4*)(c3w + oc * 128 + k8);
      const float4 v1 = *(const float4*)(c3w + oc * 128 + k8 + 4);
      uint4 q;
      q.x = (uint32_t)f2bf(v0.x) | ((uint32_t)f2bf(v0.y) << 16);
      q.y = (uint32_t)f2bf(v0.z) | ((uint32_t)f2bf(v0.w) << 16);
      q.z = (uint32_t)f2bf(v1.x) | ((uint32_t)f2bf(v1.y) << 16);
      q.w = (uint32_t)f2bf(v1.z) | ((uint32_t)f2bf(v1.w) << 16);
      const int off = ((((oc >> 4) * 4 + (k8 >> 5)) * 4 + ((k8 & 31) >> 3)) * 16 + (oc & 15)) * 8;
      *(uint4*)(w3qf + off) = q;
    }
  }

  const float* xb = x + (size_t)b * 2 * NPT;
  float px[16], py[16], dst[16];
  __shared__ float lpx[NPT], lpy[NPT];          // 64 KB point cache
  __shared__ u64 slot[2][8];
  __shared__ float cxs[NC], cys[NC];
#pragma unroll
  for (int k = 0; k < 16; k++) {
    const int id = t + k * 512;
    px[k] = xb[id];
    py[k] = xb[NPT + id];
    lpx[id] = px[k];
    lpy[id] = py[k];
  }
  const float c0x = xb[0], c0y = xb[NPT];       // broadcast loads
  if (t == 0) { cxs[0] = c0x; cys[0] = c0y; }
  float bm = -1.0f;
  int bi = 0;
#pragma unroll
  for (int k = 0; k < 16; k++) {
    const float dx = __fsub_rn(c0x, px[k]);
    const float dy = __fsub_rn(c0y, py[k]);
    dst[k] = __fadd_rn(__fmul_rn(dx, dx), __fmul_rn(dy, dy));
    if (dst[k] > bm) { bm = dst[k]; bi = t + k * 512; }
  }
  u64 best = ((u64)__float_as_uint(bm) << 32) | (uint32_t)~(uint32_t)bi;
  __syncthreads();                              // lpx/lpy visible
  for (int j = 1; j < NC; j++) {
#pragma unroll
    for (int off = 1; off < 64; off <<= 1) {
      const u64 o = __shfl_xor(best, off);
      if (o > best) best = o;
    }
    const int pb = j & 1;
    if (lane == 0) slot[pb][wid] = best;
    __syncthreads();
    u64 w = slot[pb][0];
#pragma unroll
    for (int s = 1; s < 8; s++) {
      const u64 o = slot[pb][s];
      if (o > w) w = o;
    }
    const int wi = (int)~(uint32_t)w;
    const float wx = lpx[wi], wy = lpy[wi];
    if (t == 0) { cxs[j] = wx; cys[j] = wy; }
    bm = -1.0f;
    bi = 0;
#pragma unroll
    for (int k = 0; k < 16; k++) {
      const float dx = __fsub_rn(wx, px[k]);
      const float dy = __fsub_rn(wy, py[k]);
      const float nd = __fadd_rn(__fmul_rn(dx, dx), __fmul_rn(dy, dy));
      dst[k] = fminf(dst[k], nd);
      if (dst[k] > bm) { bm = dst[k]; bi = t + k * 512; }
    }
    best = ((u64)__float_as_uint(bm) << 32) | (uint32_t)~(uint32_t)bi;
  }
  __syncthreads();
  if (t < NC) {
    cents[(size_t)b * 64 + t]      = cxs[t];
    cents[(size_t)b * 64 + 32 + t] = cys[t];
  }
}

// ---------------------------------------------------------------------------
// 2) Grouping v3: 8 CENTROIDS per block. Grid 512 = 4 cgroups x 128 batches.
// ---------------------------------------------------------------------------
__global__ __launch_bounds__(512) void group_kernel(const float* __restrict__ x,
                                                    const float* __restrict__ cents,
                                                    float* __restrict__ gx,
                                                    float* __restrict__ gy,
                                                    float* __restrict__ pmom) {
  const int b  = blockIdx.x & 127;
  const int cg = blockIdx.x >> 7;               // 0..3 -> centroids cg*8..cg*8+7
  const int t = threadIdx.x;
  const int lane = t & 63, wid = t >> 6;
  const float* px = x + (size_t)b * 2 * NPT;
  const float* py = px + NPT;
  const int p0 = t * 16;

  float lx[16], ly[16], sp[16];
#pragma unroll
  for (int k = 0; k < 16; k += 4) {
    const float4 vx = *(const float4*)(px + p0 + k);
    const float4 vy = *(const float4*)(py + p0 + k);
    lx[k] = vx.x; lx[k + 1] = vx.y; lx[k + 2] = vx.z; lx[k + 3] = vx.w;
    ly[k] = vy.x; ly[k + 1] = vy.y; ly[k + 2] = vy.z; ly[k + 3] = vy.w;
  }
#pragma unroll
  for (int k = 0; k < 16; k++)
    sp[k] = __fadd_rn(__fmul_rn(lx[k], lx[k]), __fmul_rn(ly[k], ly[k]));

  __shared__ int idxs[8][NK];
  __shared__ int wtot[8][8];
  uint32_t mask[8];
  int ebase[8];

#pragma unroll
  for (int c = 0; c < 8; c++) {
    const int cc = cg * 8 + c;
    const float cx = cents[(size_t)b * 64 + cc];
    const float cy = cents[(size_t)b * 64 + 32 + cc];
    const float sc = __fadd_rn(__fmul_rn(cx, cx), __fmul_rn(cy, cy));
    uint32_t m = 0;
#pragma unroll
    for (int k = 0; k < 16; k++) {
      const float dot = __fadd_rn(__fmul_rn(cx, lx[k]), __fmul_rn(cy, ly[k]));
      const float sq  = __fadd_rn(__fadd_rn(__fmul_rn(-2.0f, dot), sc), sp[k]);
      if (!(sq > R2)) m |= (1u << k);
    }
    mask[c] = m;
    const int cnt = (int)__popc(m);
    int pre = cnt;                              // inclusive scan within wave
#pragma unroll
    for (int off = 1; off < 64; off <<= 1) {
      const int o = __shfl_up(pre, off);
      if (lane >= off) pre += o;
    }
    ebase[c] = pre - cnt;                       // exclusive within wave
    if (lane == 63) wtot[c][wid] = pre;         // wave total
  }
  __syncthreads();
#pragma unroll
  for (int c = 0; c < 8; c++) {
    int off = 0;
#pragma unroll
    for (int w = 0; w < 8; w++) off += (w < wid) ? wtot[c][w] : 0;
    int pos = ebase[c] + off;                   // global ordered position
    uint32_t m = mask[c];
    while (m && pos < NK) {
      const int k = __ffs(m) - 1;
      idxs[c][pos] = p0 + k;
      m &= m - 1;
      pos++;
    }
  }
  __syncthreads();
  {                                             // pad short groups with idxs[0]
    int tot = 0;
#pragma unroll
    for (int w = 0; w < 8; w++) tot += wtot[wid][w];
    if (lane >= tot && lane < NK) idxs[wid][lane] = idxs[wid][0];
  }
  __syncthreads();
  {                                             // gather + fused moments (wave=cent)
    const int bc = b * 32 + cg * 8 + wid;
    float gxv = 0.f, gyv = 0.f;
    if (lane < NK) {
      const int id = idxs[wid][lane];
      gxv = px[id];
      gyv = py[id];
      const size_t s = (size_t)bc * NK + lane;
      gx[s] = gxv;
      gy[s] = gyv;
    }
    float sx = gxv, sy = gyv;
    float sxx = gxv * gxv, syy = gyv * gyv, sxy = gxv * gyv;
#pragma unroll
    for (int off = 1; off < 64; off <<= 1) {
      sx  += __shfl_xor(sx, off);
      sy  += __shfl_xor(sy, off);
      sxx += __shfl_xor(sxx, off);
      syy += __shfl_xor(syy, off);
      sxy += __shfl_xor(sxy, off);
    }
    if (lane == 0) {
      pmom[0 * 4096 + bc] = sx;
      pmom[1 * 4096 + bc] = sy;
      pmom[2 * 4096 + bc] = sxx;
      pmom[3 * 4096 + bc] = syy;
      pmom[4 * 4096 + bc] = sxy;
    }
  }
}

// bn1 scale/shift from moments: h1_c = w0*x + w1*y (bias BN-invariant, dropped)
__global__ __launch_bounds__(256) void bn1fin_kernel(const float* __restrict__ pmom,
                                                     const float* __restrict__ w,
                                                     const float* __restrict__ gamma,
                                                     const float* __restrict__ beta,
                                                     float* __restrict__ sc,
                                                     float* __restrict__ sh) {
  const int t = threadIdx.x, lane = t & 63, wid = t >> 6;
  __shared__ float rr[5][4];
  __shared__ float red[5];
#pragma unroll
  for (int m = 0; m < 5; m++) {
    float a = 0.f;
#pragma unroll
    for (int i = 0; i < 4; i++) {
      const float4 v = *(const float4*)(pmom + m * 4096 + (t + i * 256) * 4);
      a += v.x + v.y + v.z + v.w;
    }
#pragma unroll
    for (int off = 1; off < 64; off <<= 1) a += __shfl_xor(a, off);
    if (lane == 0) rr[m][wid] = a;
  }
  __syncthreads();
  if (t == 0) {
#pragma unroll
    for (int m = 0; m < 5; m++) red[m] = rr[m][0] + rr[m][1] + rr[m][2] + rr[m][3];
  }
  __syncthreads();
  if (t < 64) {
    const double invM = 1.0 / (double)MSP;
    const double mx = red[0] * invM, my = red[1] * invM;
    const double exx = red[2] * invM, eyy = red[3] * invM, exy = red[4] * invM;
    const double w0 = w[2 * t], w1 = w[2 * t + 1];
    const double mean = w0 * mx + w1 * my;
    double var = w0 * w0 * (exx - mx * mx) + 2.0 * w0 * w1 * (exy - mx * my)
               + w1 * w1 * (eyy - my * my);
    if (var < 0.0) var = 0.0;
    const double s = (double)gamma[t] / sqrt(var + 1e-5);
    sc[t] = (float)s;
    sh[t] = (float)((double)beta[t] - mean * s);
  }
}

// ---------------------------------------------------------------------------
// BN finalize: partials -> scale/shift (+ optional per-k expanded copy)
// ---------------------------------------------------------------------------
__global__ __launch_bounds__(256) void finalize_kernel(
    const float* __restrict__ psum, const float* __restrict__ psq,
    int P, float invM,
    const float* __restrict__ gamma, const float* __restrict__ beta,
    float* __restrict__ scale, float* __restrict__ shift,
    float* __restrict__ scexp, float* __restrict__ shexp, int expand) {
  const int c = blockIdx.x, t = threadIdx.x;
  float s = 0.f, q = 0.f;
  for (int p = t; p < P; p += 256) {
    s += psum[(size_t)c * P + p];
    q += psq[(size_t)c * P + p];
  }
#pragma unroll
  for (int off = 1; off < 64; off <<= 1) {
    s += __shfl_xor(s, off);
    q += __shfl_xor(q, off);
  }
  __shared__ float r1[4], r2[4], bc2[2];
  if ((t & 63) == 0) { r1[t >> 6] = s; r2[t >> 6] = q; }
  __syncthreads();
  if (t == 0) {
    s = r1[0] + r1[1] + r1[2] + r1[3];
    q = r2[0] + r2[1] + r2[2] + r2[3];
    const float m = s * invM;
    float v = fmaf(-m, m, q * invM);
    v = fmaxf(v, 0.f);
    const float sc = gamma[c] * (float)(1.0 / sqrt((double)v + 1e-5));
    const float sh = fmaf(-m, sc, beta[c]);
    scale[c] = sc;
    shift[c] = sh;
    bc2[0] = sc;
    bc2[1] = sh;
  }
  __syncthreads();
  if (t < expand) {
    scexp[c * expand + t] = bc2[0];
    shexp[c * expand + t] = bc2[1];
  }
}

// ---------------------------------------------------------------------------
// column BN (fc layers)
// ---------------------------------------------------------------------------
__global__ __launch_bounds__(256) void bncol_kernel(
    const float* __restrict__ in, int rows, int cols,
    const float* __restrict__ gamma, const float* __restrict__ beta,
    float* __restrict__ scale, float* __restrict__ shift) {
  const int jl = threadIdx.x & 63;
  const int rg = threadIdx.x >> 6;            // 0..3
  const int j = blockIdx.x * 64 + jl;
  float s = 0.f, q = 0.f;
  for (int r = rg; r < rows; r += 4) {
    const float v = in[(size_t)r * cols + j];
    s += v;
    q = fmaf(v, v, q);
  }
  __shared__ float rs[4][64], rq[4][64];
  rs[rg][jl] = s;
  rq[rg][jl] = q;
  __syncthreads();
  if (rg == 0) {
    s = rs[0][jl] + rs[1][jl] + rs[2][jl] + rs[3][jl];
    q = rq[0][jl] + rq[1][jl] + rq[2][jl] + rq[3][jl];
    const float m = s / (float)rows;
    float var = q / (float)rows - m * m;
    var = fmaxf(var, 0.f);
    const float sc = gamma[j] * (float)(1.0 / sqrt((double)var + 1e-5));
    scale[j] = sc;
    shift[j] = fmaf(-m, sc, beta[j]);
  }
}

// ---------------------------------------------------------------------------
// conv2 FUSED (conv1 inlined): D[oc][s], K=64, 512 thr = 8 waves (2 oc x 4 s).
// act tile [128 s][64 ch] computed from gx/gy on stage (bn1+relu+bf16).
// Emits h2q + bn2 partial stats (psum/psq).
// ---------------------------------------------------------------------------
__global__ __launch_bounds__(512) void conv2fused_kernel(
    const float* __restrict__ gx, const float* __restrict__ gy,
    const float* __restrict__ w1,     // conv1 weights [64][2] fp32
    const float* __restrict__ sc1, const float* __restrict__ sh1,
    const u16* __restrict__ wq,       // w2q [128][64] bf16
    u16* __restrict__ outq,           // h2q [S][128] bf16
    float* __restrict__ psum, float* __restrict__ psq) {   // [128][1024]
  constexpr int K = 64, OCB = 128, BS = 128, OCT = 128;
  constexpr int RB = K * 2;                       // 128 row bytes
  constexpr int STAGE = (OCB + BS) * RB;          // 32768
  constexpr int EPI = BS * OCB * 2 + 4 * OCB * 2 * 4;   // 36864
  constexpr int SMEM = STAGE > EPI ? STAGE : EPI;
  __shared__ __align__(16) char smem[SMEM + 1024];
  char* Wl = smem;                                // [128][64] bf16, byte^=(oc&7)<<4
  char* Bl = smem + OCB * RB;                     // [128][64] bf16, byte^=(s&7)<<4
  float* par = (float*)(smem + SMEM);             // w0[64] w1[64] sc[64] sh[64]
  const int t = threadIdx.x;
  const int lane = t & 63, wid = t >> 6;
  const int sblk = blockIdx.x;
  const int s_base = sblk * BS;

  if (t < 64) {
    par[t]       = w1[t * 2];
    par[64 + t]  = w1[t * 2 + 1];
    par[128 + t] = sc1[t];
    par[192 + t] = sh1[t];
  }
  __syncthreads();                                // par visible

  // ---- async W -> LDS (swizzled source, linear dest); overlaps act compute
  {
    constexpr int CH = OCB * RB / 16, PW = CH / 8, NI = PW / 64;  // 1024,128,2
#pragma unroll
    for (int j = 0; j < NI; j++) {
      const int c = wid * PW + j * 64 + lane;
      const int b = c * 16;
      const int oc = b / RB;
      const int off = b & (RB - 1);
      gload16((const char*)wq + (size_t)oc * RB + (off ^ ((oc & 7) << 4)),
              Wl + (wid * PW + j * 64) * 16);
    }
  }
  // ---- act tile from gx/gy (fused conv1: bn1+relu, bit-identical chain)
  {
    const int sl = t >> 2;                        // 0..127
    const int cq = t & 3;                         // 16-channel group
    const float xx = gx[s_base + sl], yy = gy[s_base + sl];
    uint32_t pk[8];
#pragma unroll
    for (int h = 0; h < 8; h++) {
      const int c = cq * 16 + 2 * h;
      float v0 = fmaf(par[c],     xx, par[64 + c]     * yy);
      float v1 = fmaf(par[c + 1], xx, par[64 + c + 1] * yy);
      v0 = fmaxf(fmaf(v0, par[128 + c],     par[192 + c]),     0.f);
      v1 = fmaxf(fmaf(v1, par[128 + c + 1], par[192 + c + 1]), 0.f);
      pk[h] = (uint32_t)f2bf(v0) | ((uint32_t)f2bf(v1) << 16);
    }
    *(uint4*)(Bl + sl * RB + ((cq * 32)      ^ ((sl & 7) << 4))) = *(uint4*)&pk[0];
    *(uint4*)(Bl + sl * RB + ((cq * 32 + 16) ^ ((sl & 7) << 4))) = *(uint4*)&pk[4];
  }
  __syncthreads();                                // W gloads drained + Bl visible

  // ---- MFMA main: wave (wr,wc) computes oc[wr*64..+64) x s[wc*32..+32)
  const int wr = wid >> 2, wc = wid & 3;
  const int l15 = lane & 15, l4 = lane >> 4;
  f32x4 acc[4][2];
#pragma unroll
  for (int fo = 0; fo < 4; fo++)
#pragma unroll
    for (int fs = 0; fs < 2; fs++)
#pragma unroll
      for (int q = 0; q < 4; q++) acc[fo][fs][q] = 0.f;

#pragma unroll
  for (int ks = 0; ks < K / 32; ks++) {
    short8v a[4], bv[2];
#pragma unroll
    for (int f = 0; f < 4; f++) {
      const int oc = wr * 64 + f * 16 + l15;
      a[f] = *(const short8v*)(Wl + oc * RB + ((ks * 64 + l4 * 16) ^ ((oc & 7) << 4)));
    }
#pragma unroll
    for (int f = 0; f < 2; f++) {
      const int sl = wc * 32 + f * 16 + l15;
      bv[f] = *(const short8v*)(Bl + sl * RB + ((ks * 64 + l4 * 16) ^ ((sl & 7) << 4)));
    }
#pragma unroll
    for (int fo = 0; fo < 4; fo++)
#pragma unroll
      for (int fs = 0; fs < 2; fs++)
        acc[fo][fs] = __builtin_amdgcn_mfma_f32_16x16x32_bf16(a[fo], bv[fs], acc[fo][fs], 0, 0, 0);
  }
  __syncthreads();   // staging LDS dead; reuse for epilogue

  char* Dl = smem;                                // [BS][OCB] bf16 swizzled
  float* sred1 = (float*)(smem + BS * OCB * 2);
  float* sred2 = sred1 + 4 * OCB;

#pragma unroll
  for (int fo = 0; fo < 4; fo++)
#pragma unroll
    for (int r = 0; r < 4; r++) {
      float s1 = acc[fo][0][r] + acc[fo][1][r];
      float s2 = fmaf(acc[fo][0][r], acc[fo][0][r], acc[fo][1][r] * acc[fo][1][r]);
#pragma unroll
      for (int off = 1; off < 16; off <<= 1) {
        s1 += __shfl_xor(s1, off);
        s2 += __shfl_xor(s2, off);
      }
      if (l15 == 0) {
        const int ocl = wr * 64 + fo * 16 + l4 * 4 + r;
        sred1[wc * OCB + ocl] = s1;
        sred2[wc * OCB + ocl] = s2;
      }
    }

#pragma unroll
  for (int fo = 0; fo < 4; fo++)
#pragma unroll
    for (int fs = 0; fs < 2; fs++) {
      const int sl = wc * 32 + fs * 16 + l15;
      const int ocl = wr * 64 + fo * 16 + l4 * 4;
      uint2 q;
      q.x = (uint32_t)f2bf(acc[fo][fs][0]) | ((uint32_t)f2bf(acc[fo][fs][1]) << 16);
      q.y = (uint32_t)f2bf(acc[fo][fs][2]) | ((uint32_t)f2bf(acc[fo][fs][3]) << 16);
      *(uint2*)(Dl + sl * 256 + ((ocl * 2) ^ ((sl & 7) << 4))) = q;
    }
  __syncthreads();

  if (t < OCB) {
    psum[(size_t)t * 1024 + sblk] =
        sred1[t] + sred1[OCB + t] + sred1[2 * OCB + t] + sred1[3 * OCB + t];
    psq[(size_t)t * 1024 + sblk] =
        sred2[t] + sred2[OCB + t] + sred2[2 * OCB + t] + sred2[3 * OCB + t];
  }
#pragma unroll
  for (int i = 0; i < 4; i++) {
    const int c = t + i * 512;                   // 2048 16B-chunks
    const int sl = c >> 4, slot = c & 15;
    const uint4 v = *(const uint4*)(Dl + sl * 256 + ((slot * 16) ^ ((sl & 7) << 4)));
    *(uint4*)(outq + (size_t)(s_base + sl) * OCT + slot * 8) = v;
  }
}

// ---------------------------------------------------------------------------
// conv3 v4: one-shot, 512 thr = 8 waves (2s x 4oc) covering ALL 256 oc.
// W in REGISTERS from frag-ordered w3qf; act tile 64s x 128k in LDS
// (bn2+relu applied on stage). SWAPPED MFMA: D[s][oc]; stats+max at gid=32s.
// ---------------------------------------------------------------------------
__global__ __launch_bounds__(512) void conv3_kernel(
    const u16* __restrict__ act,      // h2q [S][128] bf16 (raw, pre-bn2)
    const u16* __restrict__ wqf,      // frag-ordered [256][128]
    const float* __restrict__ ascale, const float* __restrict__ ashift,  // bn2, len 128
    float* __restrict__ psum, float* __restrict__ psq,   // [256][4096]
    float* __restrict__ maxpre) {     // [256][4096]
  constexpr int K = 128, RB = 256;
  __shared__ __align__(16) char Bl[64 * RB];      // 16KB act tile, swizzled
  const int t = threadIdx.x;
  const int lane = t & 63, wid = t >> 6;
  const int ws = wid & 1, wo = wid >> 1;          // s-half (0..1), oc-quarter (0..3)
  const int sblk = blockIdx.x;                    // 0..2047: 64-row s-tile
  const int l15 = lane & 15, l4 = lane >> 4;
  const int s_base = sblk * 64;

  // ---- W frags into registers: b[fo][ks], coalesced 1KB loads
  short8v b[4][4];
  {
    const int ocq0 = wo * 4;
#pragma unroll
    for (int fo = 0; fo < 4; fo++)
#pragma unroll
      for (int ks = 0; ks < 4; ks++)
        b[fo][ks] = *(const short8v*)(wqf + ((((ocq0 + fo) * 4 + ks) * 4 + l4) * 16 + l15) * 8);
  }

  // ---- stage act tile with bn2+relu (reg -> transform -> swizzled LDS)
  {
    const int kk0 = (t & 15) * 8;
    const float4 scA = *(const float4*)(ascale + kk0);
    const float4 scB = *(const float4*)(ascale + kk0 + 4);
    const float4 shA = *(const float4*)(ashift + kk0);
    const float4 shB = *(const float4*)(ashift + kk0 + 4);
    const float scr[8] = {scA.x, scA.y, scA.z, scA.w, scB.x, scB.y, scB.z, scB.w};
    const float shr[8] = {shA.x, shA.y, shA.z, shA.w, shB.x, shB.y, shB.z, shB.w};
#pragma unroll
    for (int i = 0; i < 2; i++) {
      const int sl = (t >> 4) + i * 32;
      const uint4 raw = *(const uint4*)(act + (size_t)(s_base + sl) * K + kk0);
      const u16* rp = (const u16*)&raw;
      uint32_t pk[4];
#pragma unroll
      for (int h = 0; h < 4; h++) {
        const float f0 = fmaxf(fmaf(bf2f(rp[2 * h]),     scr[2 * h],     shr[2 * h]),     0.f);
        const float f1 = fmaxf(fmaf(bf2f(rp[2 * h + 1]), scr[2 * h + 1], shr[2 * h + 1]), 0.f);
        pk[h] = (uint32_t)f2bf(f0) | ((uint32_t)f2bf(f1) << 16);
      }
      *(uint4*)(Bl + sl * RB + ((kk0 * 2) ^ ((sl & 7) << 4))) = *(uint4*)pk;
    }
  }
  __syncthreads();

  // ---- swapped MFMA: A = act (s side), B = W (oc side) -> D[s][oc]
  f32x4 acc[2][4];
#pragma unroll
  for (int fs = 0; fs < 2; fs++)
#pragma unroll
    for (int fo = 0; fo < 4; fo++)
#pragma unroll
      for (int q = 0; q < 4; q++) acc[fs][fo][q] = 0.f;

#pragma unroll
  for (int ks = 0; ks < 4; ks++) {
    short8v a[2];
#pragma unroll
    for (int fs = 0; fs < 2; fs++) {
      const int srow = ws * 32 + fs * 16 + l15;
      a[fs] = *(const short8v*)(Bl + srow * RB + ((ks * 64 + l4 * 16) ^ ((srow & 7) << 4)));
    }
#pragma unroll
    for (int fs = 0; fs < 2; fs++)
#pragma unroll
      for (int fo = 0; fo < 4; fo++)
        acc[fs][fo] = __builtin_amdgcn_mfma_f32_16x16x32_bf16(a[fs], b[fo][ks], acc[fs][fo], 0, 0, 0);
  }

  // ---- epilogue: per oc column, sum/sq/max over this wave's 32 s
  const int gid = sblk * 2 + ws;                  // 32-s pool group id
#pragma unroll
  for (int fo = 0; fo < 4; fo++) {
    float s1 = acc[0][fo][0], s2 = acc[0][fo][0] * acc[0][fo][0];
    float mx = acc[0][fo][0];
#pragma unroll
    for (int fs = 0; fs < 2; fs++)
#pragma unroll
      for (int r = 0; r < 4; r++) {
        if (fs == 0 && r == 0) continue;
        const float v = acc[fs][fo][r];
        s1 += v;
        s2 = fmaf(v, v, s2);
        mx = fmaxf(mx, v);
      }
    s1 += __shfl_xor(s1, 16); s1 += __shfl_xor(s1, 32);
    s2 += __shfl_xor(s2, 16); s2 += __shfl_xor(s2, 32);
    mx = fmaxf(mx, __shfl_xor(mx, 16));
    mx = fmaxf(mx, __shfl_xor(mx, 32));
    if (l4 == 0) {
      const int oc = wo * 64 + fo * 16 + l15;
      psum[(size_t)oc * 4096 + gid] = s1;
      psq [(size_t)oc * 4096 + gid] = s2;
      maxpre[(size_t)oc * 4096 + gid] = mx;
    }
  }
}

// ---------------------------------------------------------------------------
// fc1/fc2 via MFMA with in-register bf16 hi/lo SPLIT (fp32-class accuracy).
// T14 async-stage split: next k-chunk's W/A float4 loads issued into
// registers right after the barrier, hiding HBM latency under the MFMAs.
// ---------------------------------------------------------------------------
template <int KL, bool TRANS, bool GATHER>
__global__ __launch_bounds__(512) void fcmfma_kernel(
    const float* __restrict__ A,      // [128][Ktot] fp32, or maxpre if GATHER
    const float* __restrict__ W,      // [Ntot][Ktot] fp32
    const float* __restrict__ ascale, const float* __restrict__ ashift,
    float* __restrict__ part,         // [Ktot/KL][128][Ntot]
    int Ntot, int Ktot) {
  __shared__ __align__(16) char smem[65536];
  char* Wh = smem;                    // each [128][64] bf16, rowbytes 128,
  char* Wl = smem + 16384;            // byte ^= (row&7)<<4
  char* Ah = smem + 32768;
  char* Al = smem + 49152;
  const int t = threadIdx.x;
  const int lane = t & 63, wid = t >> 6;
  const int sblk = blockIdx.x;        // k-split index
  const int n_base = blockIdx.y * 128;
  const int k_begin = sblk * KL;
  const int kq = t & 15;              // float4-slot in row (constant per thread)
  const int r0 = t >> 4;              // rows r0, r0+32, r0+64, r0+96
  const int kk = kq * 4;
  const int wn = wid & 1, wm = wid >> 1;
  const int l15 = lane & 15, l4 = lane >> 4;

  f32x4 acc[4][2];
#pragma unroll
  for (int fo = 0; fo < 4; fo++)
#pragma unroll
    for (int fs = 0; fs < 2; fs++)
#pragma unroll
      for (int q = 0; q < 4; q++) acc[fo][fs][q] = 0.f;

  float4 wv[4], av[4], tsc, tsh;
  // ---- prologue: load chunk 0 into registers
  {
    const int kabs = k_begin + kk;
    if constexpr (TRANS) {
      tsc = *(const float4*)(ascale + kabs);
      tsh = *(const float4*)(ashift + kabs);
    }
#pragma unroll
    for (int i = 0; i < 4; i++) {
      const int row = r0 + i * 32;
      wv[i] = *(const float4*)(W + (size_t)(n_base + row) * Ktot + kabs);
      if constexpr (GATHER)
        av[i] = *(const float4*)(A + (size_t)(kabs >> 5) * 4096 + row * 32 + (kabs & 31));
      else
        av[i] = *(const float4*)(A + (size_t)row * Ktot + kabs);
    }
  }

  for (int c0 = 0; c0 < KL; c0 += 64) {
    // ---- convert current regs -> LDS (same chain as before)
#pragma unroll
    for (int i = 0; i < 4; i++) {
      const int row = r0 + i * 32;
      const int byte = row * 128 + ((kk * 2) ^ ((row & 7) << 4));
      {
        const float4 v = wv[i];
        const u16 h0 = f2bf(v.x), h1 = f2bf(v.y), h2 = f2bf(v.z), h3 = f2bf(v.w);
        uint2 hv, lv;
        hv.x = (uint32_t)h0 | ((uint32_t)h1 << 16);
        hv.y = (uint32_t)h2 | ((uint32_t)h3 << 16);
        lv.x = (uint32_t)f2bf(v.x - bf2f(h0)) | ((uint32_t)f2bf(v.y - bf2f(h1)) << 16);
        lv.y = (uint32_t)f2bf(v.z - bf2f(h2)) | ((uint32_t)f2bf(v.w - bf2f(h3)) << 16);
        *(uint2*)(Wh + byte) = hv;
        *(uint2*)(Wl + byte) = lv;
      }
      {
        float4 v = av[i];
        if constexpr (TRANS) {
          v.x = fmaxf(fmaf(v.x, tsc.x, tsh.x), 0.f);
          v.y = fmaxf(fmaf(v.y, tsc.y, tsh.y), 0.f);
          v.z = fmaxf(fmaf(v.z, tsc.z, tsh.z), 0.f);
          v.w = fmaxf(fmaf(v.w, tsc.w, tsh.w), 0.f);
        }
        const u16 h0 = f2bf(v.x), h1 = f2bf(v.y), h2 = f2bf(v.z), h3 = f2bf(v.w);
        uint2 hv, lv;
        hv.x = (uint32_t)h0 | ((uint32_t)h1 << 16);
        hv.y = (uint32_t)h2 | ((uint32_t)h3 << 16);
        lv.x = (uint32_t)f2bf(v.x - bf2f(h0)) | ((uint32_t)f2bf(v.y - bf2f(h1)) << 16);
        lv.y = (uint32_t)f2bf(v.z - bf2f(h2)) | ((uint32_t)f2bf(v.w - bf2f(h3)) << 16);
        *(uint2*)(Ah + byte) = hv;
        *(uint2*)(Al + byte) = lv;
      }
    }
    __syncthreads();
    // ---- prefetch next chunk (loads stay in flight across the MFMA phase)
    if (c0 + 64 < KL) {
      const int kabs = k_begin + c0 + 64 + kk;
      if constexpr (TRANS) {
        tsc = *(const float4*)(ascale + kabs);
        tsh = *(const float4*)(ashift + kabs);
      }
#pragma unroll
      for (int i = 0; i < 4; i++) {
        const int row = r0 + i * 32;
        wv[i] = *(const float4*)(W + (size_t)(n_base + row) * Ktot + kabs);
        if constexpr (GATHER)
          av[i] = *(const float4*)(A + (size_t)(kabs >> 5) * 4096 + row * 32 + (kabs & 31));
        else
          av[i] = *(const float4*)(A + (size_t)row * Ktot + kabs);
      }
    }
    // ---- MFMA phase
#pragma unroll
    for (int ks = 0; ks < 2; ks++) {
      short8v ah[4], al_[4], bh[2], bl[2];
#pragma unroll
      for (int f = 0; f < 4; f++) {
        const int r = wn * 64 + f * 16 + l15;
        const int byte = r * 128 + ((ks * 64 + l4 * 16) ^ ((r & 7) << 4));
        ah[f]  = *(const short8v*)(Wh + byte);
        al_[f] = *(const short8v*)(Wl + byte);
      }
#pragma unroll
      for (int f = 0; f < 2; f++) {
        const int r = wm * 32 + f * 16 + l15;
        const int byte = r * 128 + ((ks * 64 + l4 * 16) ^ ((r & 7) << 4));
        bh[f] = *(const short8v*)(Ah + byte);
        bl[f] = *(const short8v*)(Al + byte);
      }
#pragma unroll
      for (int fo = 0; fo < 4; fo++)
#pragma unroll
        for (int fs = 0; fs < 2; fs++) {
          acc[fo][fs] = __builtin_amdgcn_mfma_f32_16x16x32_bf16(ah[fo],  bh[fs], acc[fo][fs], 0, 0, 0);
          acc[fo][fs] = __builtin_amdgcn_mfma_f32_16x16x32_bf16(ah[fo],  bl[fs], acc[fo][fs], 0, 0, 0);
          acc[fo][fs] = __builtin_amdgcn_mfma_f32_16x16x32_bf16(al_[fo], bh[fs], acc[fo][fs], 0, 0, 0);
        }
    }
    __syncthreads();
  }
  // epilogue: D row = n (W side), col = m (batch side)
#pragma unroll
  for (int fo = 0; fo < 4; fo++) {
    const int n0 = n_base + wn * 64 + fo * 16 + l4 * 4;
#pragma unroll
    for (int fs = 0; fs < 2; fs++) {
      const int m = wm * 32 + fs * 16 + l15;
      *(float4*)(part + ((size_t)sblk * 128 + m) * Ntot + n0) =
          make_float4(acc[fo][fs][0], acc[fo][fs][1], acc[fo][fs][2], acc[fo][fs][3]);
    }
  }
}

// out[id] = sum_p part[p][id]  (id over 128*Ntot)
__global__ __launch_bounds__(256) void fcreduce_kernel(const float* __restrict__ part,
                                                       float* __restrict__ out,
                                                       int total, int S) {
  const int id = blockIdx.x * 256 + threadIdx.x;
  if (id >= total) return;
  float s = 0.f;
  for (int p = 0; p < S; p++) s += part[(size_t)p * total + id];
  out[id] = s;
}

// ---------------------------------------------------------------------------
// tail v3 (256 thr): bnrelu5 -> fc3 (8x8-lane split dot) -> mu/logvar -> z
// -> decoder -> outputs.
// ---------------------------------------------------------------------------
__global__ __launch_bounds__(256) void tail_kernel(
    const float* __restrict__ fc2raw, const float* __restrict__ scale5, const float* __restrict__ shift5,
    const float* __restrict__ w3, const float* __restrict__ b3,
    const float* __restrict__ e1w, const float* __restrict__ e1b,
    const float* __restrict__ e2w, const float* __restrict__ e2b,
    const float* __restrict__ eps,
    const float* __restrict__ d1w, const float* __restrict__ d1b,
    const float* __restrict__ d2w, const float* __restrict__ d2b,
    const float* __restrict__ d3w, const float* __restrict__ d3b,
    float* __restrict__ out) {
  const int b = blockIdx.x, t = threadIdx.x;
  __shared__ float h5[256], feat[8], z[8], d1[32], d2[128];
  {
    const float v = fc2raw[(size_t)b * 256 + t];
    h5[t] = fmaxf(fmaf(v, scale5[t], shift5[t]), 0.f);
  }
  __syncthreads();
  if (t < 64) {                       // fc3: 8 outputs x 8 lanes x 32 FMA
    const int o = t >> 3, p = t & 7;
    const float* wr = w3 + o * 256 + p * 32;
    const float* hr = h5 + p * 32;
    float s = 0.f;
    for (int i = 0; i < 32; i++) s = fmaf(hr[i], wr[i], s);
    s += __shfl_xor(s, 1);
    s += __shfl_xor(s, 2);
    s += __shfl_xor(s, 4);
    if (p == 0) feat[o] = fmaxf(s + b3[o], 0.f);
  }
  __syncthreads();
  if (t < 8) {
    float mu = e1b[t], lv = e2b[t];
    for (int j = 0; j < 8; j++) {
      mu = fmaf(feat[j], e1w[t * 8 + j], mu);
      lv = fmaf(feat[j], e2w[t * 8 + j], lv);
    }
    out[65536 + b * 8 + t] = mu;
    out[66560 + b * 8 + t] = lv;
    z[t] = fmaf(eps[b * 8 + t], expf(0.5f * lv), mu);
  }
  __syncthreads();
  if (t < 32) {
    float s = d1b[t];
    for (int j = 0; j < 8; j++) s = fmaf(z[j], d1w[t * 8 + j], s);
    d1[t] = fmaxf(s, 0.f);
  }
  __syncthreads();
  if (t < 128) {
    float s = d2b[t];
    for (int j = 0; j < 32; j++) s = fmaf(d1[j], d2w[t * 32 + j], s);
    d2[t] = fmaxf(s, 0.f);
  }
  __syncthreads();
  for (int o = t; o < 512; o += 256) {
    float s = d3b[o];
    for (int j = 0; j < 128; j++) s = fmaf(d2[j], d3w[o * 128 + j], s);
    out[(size_t)b * 512 + o] = s;
  }
}

// ---------------------------------------------------------------------------
extern "C" void kernel_launch(void* const* d_in, const int* in_sizes, int n_in,
                              void* d_out, int out_size, void* d_ws, size_t ws_size,
                              hipStream_t stream) {
  const float* x    = (const float*)d_in[0];
  const float* eps  = (const float*)d_in[1];
  const float* c1w  = (const float*)d_in[2];
  const float* bn1g = (const float*)d_in[4];
  const float* bn1b = (const float*)d_in[5];
  const float* c2w  = (const float*)d_in[6];
  const float* bn2g = (const float*)d_in[8];
  const float* bn2b = (const float*)d_in[9];
  const float* c3w  = (const float*)d_in[10];
  const float* bn3g = (const float*)d_in[12];
  const float* bn3b = (const float*)d_in[13];
  const float* f1w  = (const float*)d_in[14];
  const float* bn4g = (const float*)d_in[16];
  const float* bn4b = (const float*)d_in[17];
  const float* f2w  = (const float*)d_in[18];
  const float* bn5g = (const float*)d_in[20];
  const float* bn5b = (const float*)d_in[21];
  const float* f3w  = (const float*)d_in[22];
  const float* f3b  = (const float*)d_in[23];
  const float* e1w  = (const float*)d_in[24];
  const float* e1b  = (const float*)d_in[25];
  const float* e2w  = (const float*)d_in[26];
  const float* e2b  = (const float*)d_in[27];
  const float* d1w  = (const float*)d_in[28];
  const float* d1b  = (const float*)d_in[29];
  const float* d2w  = (const float*)d_in[30];
  const float* d2b  = (const float*)d_in[31];
  const float* d3w  = (const float*)d_in[32];
  const float* d3b  = (const float*)d_in[33];

  float* ws = (float*)d_ws;
  float* cents  = ws + OFF_CENTS;
  float* gx     = ws + OFF_GX;
  float* gy     = ws + OFF_GY;
  u16*   h2q    = (u16*)(ws + OFF_H2Q);
  u16*   w2q    = (u16*)(ws + OFF_W2Q);
  u16*   w3qf   = (u16*)(ws + OFF_W3Q);
  float* pmom   = ws + OFF_PMOM;
  float* maxpre = ws + OFF_MAXPRE;
  float* part1  = ws + OFF_PART1;
  float* part2  = ws + OFF_PART2;
  float* fc1o   = ws + OFF_FC1;
  float* fc2o   = ws + OFF_FC2;
  float* p2s = ws + OFF_P2S, *p2q = ws + OFF_P2Q;
  float* p3s = ws + OFF_P3S, *p3q = ws + OFF_P3Q;
  float* sc1 = ws + OFF_SC1, *sh1 = ws + OFF_SH1;
  float* sc2 = ws + OFF_SC2, *sh2 = ws + OFF_SH2;
  float* sc3 = ws + OFF_SC3, *sh3 = ws + OFF_SH3;
  float* sc4 = ws + OFF_SC4, *sh4 = ws + OFF_SH4;
  float* sc5 = ws + OFF_SC5, *sh5 = ws + OFF_SH5;
  float* sc3e = ws + OFF_SC3E, *sh3e = ws + OFF_SH3E;

  // fps v5: wquant folded into blocks 0..11; float-argmax inner loop
  fps_kernel<<<NB, 512, 0, stream>>>(x, cents, c2w, c3w, w2q, w3qf);
  // group v3: 4 cgroups x 128 batches, 8 centroids per block
  group_kernel<<<512, 512, 0, stream>>>(x, cents, gx, gy, pmom);

  bn1fin_kernel<<<1, 256, 0, stream>>>(pmom, c1w, bn1g, bn1b, sc1, sh1);

  // conv2 FUSED (conv1 inlined on stage): gx/gy -> h2q + bn2 stats
  conv2fused_kernel<<<1024, 512, 0, stream>>>(gx, gy, c1w, sc1, sh1, w2q,
                                              h2q, p2s, p2q);
  finalize_kernel<<<128, 256, 0, stream>>>(p2s, p2q, 1024, 1.f / MSP, bn2g, bn2b,
                                           sc2, sh2, nullptr, nullptr, 0);

  // conv3 v4: 512-thr blocks, one act stage per s-tile (all 256 oc in-block)
  conv3_kernel<<<2048, 512, 0, stream>>>(h2q, w3qf, sc2, sh2, p3s, p3q, maxpre);
  finalize_kernel<<<256, 256, 0, stream>>>(p3s, p3q, 4096, 1.f / MSP, bn3g, bn3b,
                                           sc3, sh3, sc3e, sh3e, 32);

  // fc1: N=1024, K=8192; KL=256, grid (32,8) -- R6 best config; T14 prefetch
  fcmfma_kernel<256, true, true><<<dim3(32, 8), 512, 0, stream>>>(
      maxpre, f1w, sc3e, sh3e, part1, 1024, 8192);
  fcreduce_kernel<<<512, 256, 0, stream>>>(part1, fc1o, 131072, 32);
  bncol_kernel<<<16, 256, 0, stream>>>(fc1o, 128, 1024, bn4g, bn4b, sc4, sh4);

  // fc2: N=256, K=1024, KL=128 -> 8 k-splits x 2 n-blocks -- R6 best config
  fcmfma_kernel<128, true, false><<<dim3(8, 2), 512, 0, stream>>>(
      fc1o, f2w, sc4, sh4, part2, 256, 1024);
  fcreduce_kernel<<<128, 256, 0, stream>>>(part2, fc2o, 32768, 8);
  bncol_kernel<<<4, 256, 0, stream>>>(fc2o, 128, 256, bn5g, bn5b, sc5, sh5);

  tail_kernel<<<NB, 256, 0, stream>>>(fc2o, sc5, sh5, f3w, f3b, e1w, e1b, e2w, e2b, eps,
                                      d1w, d1b, d2w, d2b, d3w, d3b, (float*)d_out);
}